// Round 15
// baseline (620.673 us; speedup 1.0000x reference)
//
#include <hip/hip_runtime.h>

#define NN 100000
#define EE 3200000
#define DD 256
#define CC 40
#define NCH 8
#define CH 32
#define UN2 8

#define CAPW 640              // staged edges per 16-row wave (avg 512, +5.7 sigma)
#define COHORT 256            // blocks per chunk
#define CHUNK_BLOCKS (COHORT * 8)
#define WPC (COHORT * 4)      // waves per chunk
#define WG16 (NN / 16)        // 6250 wave-groups of 16 rows
#define LROWS 64              // rows per k_linear block
#define SROWS 8               // rows per k_spmm2 block (320 threads)

#define COLMASK 0x1FFFFu      // 17 bits: col < 131072
#define VALMASK 0xFFFE0000u   // bits [31:17] = bf16 (sign 0) of val

typedef unsigned long long ull2 __attribute__((ext_vector_type(2)));

__device__ __forceinline__ float bf2f(unsigned int u) {
    return __uint_as_float(u << 16);
}
__device__ __forceinline__ unsigned short f2bf(float f) {
    unsigned int t = __float_as_uint(f);
    return (unsigned short)((t + 0x7FFFu + ((t >> 16) & 1u)) >> 16);
}
// unpack packed meta -> f32 val (bf16 bits live at [31:17], sign 0)
__device__ __forceinline__ float punpack_v(unsigned m) {
    return __uint_as_float((m & VALMASK) >> 1);
}

// ---------------- CSR row_ptr from sorted adj_row ----------------
__global__ __launch_bounds__(256) void k_row_ptr(const int* __restrict__ adj_row,
                                                 int* __restrict__ row_ptr) {
    int e = blockIdx.x * 256 + threadIdx.x;
    if (e >= EE) return;
    int r = adj_row[e];
    int prev = (e == 0) ? -1 : adj_row[e - 1];
    for (int rr = prev + 1; rr <= r; ++rr) row_ptr[rr] = e;
    if (e == EE - 1) {
        for (int rr = r + 1; rr <= NN; ++rr) row_ptr[rr] = EE;
    }
}

// ---- pack {col:17b | val-bf16(sign0):15b} into one u32 per edge ----
// val = uniform[0, 0.0625) is nonnegative -> bf16 sign bit always 0.
__global__ __launch_bounds__(256) void k_pack(const float* __restrict__ adj_vals,
                                              const int* __restrict__ adj_col,
                                              unsigned* __restrict__ pack) {
    for (int e = blockIdx.x * 256 + threadIdx.x; e < EE; e += gridDim.x * 256) {
        unsigned c = (unsigned)adj_col[e] & COLMASK;
        unsigned vb = (unsigned)f2bf(adj_vals[e]);   // 15 significant bits
        pack[e] = c | (vb << 17);
    }
}

// ---- x -> xb[8][NN][32] bf16 transpose + drop_mask -> 1-bit pack ----
__global__ __launch_bounds__(256) void k_cvt_t(const float* __restrict__ x,
                                               const float* __restrict__ drop_mask,
                                               ushort* __restrict__ xb,
                                               unsigned* __restrict__ mbits) {
    __shared__ ushort ls[32][DD + 4];
    int t = threadIdx.x;
    size_t r0 = (size_t)blockIdx.x * 32;
    const float4* src = (const float4*)(x + r0 * DD);
#pragma unroll
    for (int u = 0; u < 8; ++u) {
        int idx = u * 256 + t;
        float4 v = src[idx];
        int row = idx >> 6, d4 = idx & 63;
        ushort* p = &ls[row][d4 * 4];
        p[0] = f2bf(v.x); p[1] = f2bf(v.y); p[2] = f2bf(v.z); p[3] = f2bf(v.w);
    }
    {   // mask pack: thread t -> row r = t>>3, 32-dim segment o = t&7
        int r = t >> 3, o = t & 7;
        const float4* mp = (const float4*)(drop_mask + (r0 + r) * DD + o * 32);
        unsigned bits = 0;
#pragma unroll
        for (int qq = 0; qq < 8; ++qq) {
            float4 m = mp[qq];
            bits |= (m.x != 0.f ? 1u : 0u) << (qq * 4 + 0);
            bits |= (m.y != 0.f ? 1u : 0u) << (qq * 4 + 1);
            bits |= (m.z != 0.f ? 1u : 0u) << (qq * 4 + 2);
            bits |= (m.w != 0.f ? 1u : 0u) << (qq * 4 + 3);
        }
        mbits[(r0 + r) * 8 + o] = bits;
    }
    __syncthreads();
    int c = t >> 5, r = t & 31;
    const uint4* s = (const uint4*)&ls[r][c * CH];
    uint4* dst = (uint4*)(xb + ((size_t)c * NN + r0 + r) * CH);
    dst[0] = s[0];
    dst[1] = s[1];
    dst[2] = s[2];
    dst[3] = s[3];
}

// ---- chunked SpMM1 + relu + bit-dropout -> hb: per-wave staging ----
// Chunk c = bid&7 pinned to its XCD. Each wave owns 16 rows and stages its
// own contiguous edge range (packed u32 meta: 1 load/edge, 102MB replay
// instead of 205MB) into a private LDS slice; no __syncthreads.
__global__ __launch_bounds__(256, 8) void k_chunk(
    const ushort* __restrict__ xb, const unsigned* __restrict__ pack,
    const int* __restrict__ row_ptr, const unsigned* __restrict__ mbits,
    ushort* __restrict__ hb)
{
    __shared__ unsigned meta[4][CAPW];
    int bid = blockIdx.x;
    int c = bid & 7;
    int q = bid >> 3;
    int wave = threadIdx.x >> 6, lane = threadIdx.x & 63;
    int g = lane >> 2, i = lane & 3;        // row-in-16, dim-octet
    const ushort* xc = xb + (size_t)c * NN * CH;
    unsigned* mw = meta[wave];

    for (int wg = q * 4 + wave; wg < WG16; wg += WPC) {
        int row0 = wg * 16;
        int row  = row0 + g;
        int e_start = __builtin_amdgcn_readfirstlane(row_ptr[row0]);
        int e_end   = __builtin_amdgcn_readfirstlane(row_ptr[row0 + 16]);
        int nstage  = min(e_end - e_start, CAPW);

        for (int t = lane; t < nstage; t += 64)
            mw[t] = pack[e_start + t];
        asm volatile("s_waitcnt lgkmcnt(0)" ::: "memory");
        __builtin_amdgcn_wave_barrier();

        int e0  = row_ptr[row];
        int cnt = row_ptr[row + 1] - e0;
        int eloc = e0 - e_start;
        float a0 = 0.f, a1 = 0.f, a2 = 0.f, a3 = 0.f;
        float a4 = 0.f, a5 = 0.f, a6 = 0.f, a7 = 0.f;

        if (eloc + cnt <= nstage) {          // staged path (always, in practice)
            int body = cnt & ~(UN2 - 1);
            int k = 0;
            for (; k < body; k += UN2) {
                unsigned mm[UN2];
#pragma unroll
                for (int u = 0; u < UN2; ++u) mm[u] = mw[eloc + k + u];
                uint4 xv[UN2];
#pragma unroll
                for (int u = 0; u < UN2; ++u)
                    xv[u] = *(const uint4*)(xc + (size_t)(mm[u] & COLMASK) * CH + i * 8);
#pragma unroll
                for (int u = 0; u < UN2; ++u) {
                    float v = punpack_v(mm[u]);
                    a0 = fmaf(v, bf2f(xv[u].x & 0xFFFFu), a0);
                    a1 = fmaf(v, bf2f(xv[u].x >> 16),     a1);
                    a2 = fmaf(v, bf2f(xv[u].y & 0xFFFFu), a2);
                    a3 = fmaf(v, bf2f(xv[u].y >> 16),     a3);
                    a4 = fmaf(v, bf2f(xv[u].z & 0xFFFFu), a4);
                    a5 = fmaf(v, bf2f(xv[u].z >> 16),     a5);
                    a6 = fmaf(v, bf2f(xv[u].w & 0xFFFFu), a6);
                    a7 = fmaf(v, bf2f(xv[u].w >> 16),     a7);
                }
            }
            if (k < cnt) {                   // one clamped tail batch
#pragma unroll
                for (int u = 0; u < UN2; ++u) {
                    int kk = k + u;
                    unsigned m = mw[eloc + min(kk, cnt - 1)];
                    float v = (kk < cnt) ? punpack_v(m) : 0.f;
                    uint4 xv = *(const uint4*)(xc + (size_t)(m & COLMASK) * CH + i * 8);
                    a0 = fmaf(v, bf2f(xv.x & 0xFFFFu), a0);
                    a1 = fmaf(v, bf2f(xv.x >> 16),     a1);
                    a2 = fmaf(v, bf2f(xv.y & 0xFFFFu), a2);
                    a3 = fmaf(v, bf2f(xv.y >> 16),     a3);
                    a4 = fmaf(v, bf2f(xv.z & 0xFFFFu), a4);
                    a5 = fmaf(v, bf2f(xv.z >> 16),     a5);
                    a6 = fmaf(v, bf2f(xv.w & 0xFFFFu), a6);
                    a7 = fmaf(v, bf2f(xv.w >> 16),     a7);
                }
            }
        } else {                             // overflow fallback (correctness net)
            for (int k = 0; k < cnt; ++k) {
                unsigned m = pack[e0 + k];
                float v = punpack_v(m);
                uint4 xv = *(const uint4*)(xc + (size_t)(m & COLMASK) * CH + i * 8);
                a0 = fmaf(v, bf2f(xv.x & 0xFFFFu), a0);
                a1 = fmaf(v, bf2f(xv.x >> 16),     a1);
                a2 = fmaf(v, bf2f(xv.y & 0xFFFFu), a2);
                a3 = fmaf(v, bf2f(xv.y >> 16),     a3);
                a4 = fmaf(v, bf2f(xv.z & 0xFFFFu), a4);
                a5 = fmaf(v, bf2f(xv.z >> 16),     a5);
                a6 = fmaf(v, bf2f(xv.w & 0xFFFFu), a6);
                a7 = fmaf(v, bf2f(xv.w >> 16),     a7);
            }
        }
        __builtin_amdgcn_wave_barrier();     // keep next staging after reads

        {
            unsigned mb = mbits[(size_t)row * 8 + c];
            unsigned mbyte = (mb >> (i * 8)) & 0xFFu;
            float h0 = (mbyte & 1u)   ? 2.f * fmaxf(a0, 0.f) : 0.f;
            float h1 = (mbyte & 2u)   ? 2.f * fmaxf(a1, 0.f) : 0.f;
            float h2 = (mbyte & 4u)   ? 2.f * fmaxf(a2, 0.f) : 0.f;
            float h3 = (mbyte & 8u)   ? 2.f * fmaxf(a3, 0.f) : 0.f;
            float h4 = (mbyte & 16u)  ? 2.f * fmaxf(a4, 0.f) : 0.f;
            float h5 = (mbyte & 32u)  ? 2.f * fmaxf(a5, 0.f) : 0.f;
            float h6 = (mbyte & 64u)  ? 2.f * fmaxf(a6, 0.f) : 0.f;
            float h7 = (mbyte & 128u) ? 2.f * fmaxf(a7, 0.f) : 0.f;
            size_t off = (size_t)row * DD + c * CH + i * 8;
            ull2 pk;
            pk.x = (unsigned long long)((unsigned)f2bf(h0) | ((unsigned)f2bf(h1) << 16)) |
                   ((unsigned long long)((unsigned)f2bf(h2) | ((unsigned)f2bf(h3) << 16)) << 32);
            pk.y = (unsigned long long)((unsigned)f2bf(h4) | ((unsigned)f2bf(h5) << 16)) |
                   ((unsigned long long)((unsigned)f2bf(h6) | ((unsigned)f2bf(h7) << 16)) << 32);
            __builtin_nontemporal_store(pk, (ull2*)(hb + off));
        }
    }
}

// ---- Linear(256->40) as register-tiled GEMM: 64 rows/block, W in LDS ----
__global__ __launch_bounds__(256) void k_linear(
    const ushort* __restrict__ hb, const float* __restrict__ W,
    const float* __restrict__ b, ushort* __restrict__ z)
{
    __shared__ float ws[CC][DD + 4];
    int t = threadIdx.x;
    for (int idx = t; idx < CC * (DD / 4); idx += 256) {
        int c = idx >> 6, k4 = idx & 63;
        float4 v = ((const float4*)(W + (size_t)c * DD))[k4];
        float* p = &ws[c][k4 * 4];
        p[0] = v.x; p[1] = v.y; p[2] = v.z; p[3] = v.w;
    }
    __syncthreads();

    int row = blockIdx.x * LROWS + (t >> 2);
    int cg = (t & 3) * 10;
    if (row >= NN) return;

    const uint4* hrow = (const uint4*)(hb + (size_t)row * DD);
    float acc[10] = {0.f, 0.f, 0.f, 0.f, 0.f, 0.f, 0.f, 0.f, 0.f, 0.f};

    for (int k8 = 0; k8 < DD / 8; ++k8) {
        uint4 hv = hrow[k8];
        float h0 = bf2f(hv.x & 0xFFFFu), h1 = bf2f(hv.x >> 16);
        float h2 = bf2f(hv.y & 0xFFFFu), h3 = bf2f(hv.y >> 16);
        float h4 = bf2f(hv.z & 0xFFFFu), h5 = bf2f(hv.z >> 16);
        float h6 = bf2f(hv.w & 0xFFFFu), h7 = bf2f(hv.w >> 16);
#pragma unroll
        for (int j = 0; j < 10; ++j) {
            const float* wp = &ws[cg + j][k8 * 8];
            float4 wa = *(const float4*)wp;
            float4 wb = *(const float4*)(wp + 4);
            acc[j] = fmaf(h0, wa.x, fmaf(h1, wa.y,
                     fmaf(h2, wa.z, fmaf(h3, wa.w, acc[j]))));
            acc[j] = fmaf(h4, wb.x, fmaf(h5, wb.y,
                     fmaf(h6, wb.z, fmaf(h7, wb.w, acc[j]))));
        }
    }
#pragma unroll
    for (int j = 0; j < 10; ++j)
        z[(size_t)row * CC + cg + j] = f2bf(acc[j] + b[cg + j]);
}

// ---- out = SpMM(z): 320-thread blocks, thread = (row, class); z bf16 ----
// Uses ORIGINAL f32 adj_vals (second spmm keeps full val precision).
__global__ __launch_bounds__(320) void k_spmm2(
    const ushort* __restrict__ z, const float* __restrict__ adj_vals,
    const int* __restrict__ adj_col, const int* __restrict__ row_ptr,
    float* __restrict__ out)
{
    int t = threadIdx.x;
    int row = blockIdx.x * SROWS + t / CC;   // NN % 8 == 0, grid exact
    int cls = t % CC;

    int e0 = row_ptr[row], e1 = row_ptr[row + 1];
    float acc = 0.f;
    for (int base = e0; base < e1; base += UN2) {
        float vv[UN2]; int cc[UN2];
#pragma unroll
        for (int u = 0; u < UN2; ++u) {
            int idx = base + u;
            bool ok = idx < e1;
            idx = ok ? idx : e1 - 1;
            vv[u] = ok ? adj_vals[idx] : 0.f;
            cc[u] = adj_col[idx];
        }
        float za[UN2];
#pragma unroll
        for (int u = 0; u < UN2; ++u)
            za[u] = bf2f((unsigned)z[(size_t)cc[u] * CC + cls]);
#pragma unroll
        for (int u = 0; u < UN2; ++u)
            acc = fmaf(vv[u], za[u], acc);
    }
    out[(size_t)row * CC + cls] = acc;
}

extern "C" void kernel_launch(void* const* d_in, const int* in_sizes, int n_in,
                              void* d_out, int out_size, void* d_ws, size_t ws_size,
                              hipStream_t stream) {
    const float* x         = (const float*)d_in[0];
    const float* adj_vals  = (const float*)d_in[1];
    const float* W         = (const float*)d_in[2];
    const float* b         = (const float*)d_in[3];
    const float* drop_mask = (const float*)d_in[4];
    const int*   adj_row   = (const int*)d_in[5];
    const int*   adj_col   = (const int*)d_in[6];
    float* out = (float*)d_out;

    // ws: row_ptr | shared{pack u32[EE] -> later z bf16} | xb | hb | mbits
    // pack is dead after k_chunk; z (8MB) is written by k_linear into the
    // same 12.8MB region. Total ~118.8MB (<= 122MB proven in r11).
    char* wsp = (char*)d_ws;
    size_t rp_bytes = ((size_t)(NN + 1) * 4 + 255) & ~(size_t)255;
    size_t sh_bytes = (((size_t)EE * 4) + 255) & ~(size_t)255;
    size_t xb_bytes = (size_t)NN * DD * 2;
    size_t hb_bytes = (size_t)NN * DD * 2;
    int* row_ptr    = (int*)wsp;
    unsigned* pack  = (unsigned*)(wsp + rp_bytes);
    ushort* zbuf    = (ushort*)(wsp + rp_bytes);          // overlays pack
    ushort* xb      = (ushort*)(wsp + rp_bytes + sh_bytes);
    ushort* hb      = (ushort*)(wsp + rp_bytes + sh_bytes + xb_bytes);
    unsigned* mbits = (unsigned*)(wsp + rp_bytes + sh_bytes + xb_bytes + hb_bytes);

    hipLaunchKernelGGL(k_row_ptr, dim3((EE + 255) / 256), dim3(256), 0, stream,
                       adj_row, row_ptr);
    hipLaunchKernelGGL(k_pack, dim3(2048), dim3(256), 0, stream,
                       adj_vals, adj_col, pack);
    hipLaunchKernelGGL(k_cvt_t, dim3(NN / 32), dim3(256), 0, stream,
                       x, drop_mask, xb, mbits);
    hipLaunchKernelGGL(k_chunk, dim3(CHUNK_BLOCKS), dim3(256), 0, stream,
                       xb, pack, row_ptr, mbits, hb);
    hipLaunchKernelGGL(k_linear, dim3((NN + LROWS - 1) / LROWS), dim3(256), 0,
                       stream, hb, W, b, zbuf);
    hipLaunchKernelGGL(k_spmm2, dim3(NN / SROWS), dim3(320), 0, stream,
                       zbuf, adj_vals, adj_col, row_ptr, out);
}

// Round 16
// 619.761 us; speedup vs baseline: 1.0015x; 1.0015x over previous
//
#include <hip/hip_runtime.h>

#define NN 100000
#define EE 3200000
#define DD 256
#define CC 40
#define NCH 8
#define CH 32
#define UN2 8

#define CAPW 640              // staged edges per 16-row wave (avg 512, +5.7 sigma)
#define COHORT 256            // blocks per chunk
#define CHUNK_BLOCKS (COHORT * 8)
#define WPC (COHORT * 4)      // waves per chunk
#define WG16 (NN / 16)        // 6250 wave-groups of 16 rows
#define LROWS 64              // rows per k_linear block
#define SROWS 8               // rows per k_spmm2 block (320 threads)

#define COLMASK 0x1FFFFu      // 17 bits: col < 131072
#define VALMASK 0xFFFE0000u   // bits [31:17] = bf16 (sign 0) of val

__device__ __forceinline__ float bf2f(unsigned int u) {
    return __uint_as_float(u << 16);
}
__device__ __forceinline__ unsigned short f2bf(float f) {
    unsigned int t = __float_as_uint(f);
    return (unsigned short)((t + 0x7FFFu + ((t >> 16) & 1u)) >> 16);
}
// unpack packed meta -> f32 val (bf16 bits live at [31:17], sign 0)
__device__ __forceinline__ float punpack_v(unsigned m) {
    return __uint_as_float((m & VALMASK) >> 1);
}

// ---------------- CSR row_ptr from sorted adj_row ----------------
__global__ __launch_bounds__(256) void k_row_ptr(const int* __restrict__ adj_row,
                                                 int* __restrict__ row_ptr) {
    int e = blockIdx.x * 256 + threadIdx.x;
    if (e >= EE) return;
    int r = adj_row[e];
    int prev = (e == 0) ? -1 : adj_row[e - 1];
    for (int rr = prev + 1; rr <= r; ++rr) row_ptr[rr] = e;
    if (e == EE - 1) {
        for (int rr = r + 1; rr <= NN; ++rr) row_ptr[rr] = EE;
    }
}

// ---- pack {col:17b | val-bf16(sign0):15b} into one u32 per edge ----
__global__ __launch_bounds__(256) void k_pack(const float* __restrict__ adj_vals,
                                              const int* __restrict__ adj_col,
                                              unsigned* __restrict__ pack) {
    for (int e = blockIdx.x * 256 + threadIdx.x; e < EE; e += gridDim.x * 256) {
        unsigned c = (unsigned)adj_col[e] & COLMASK;
        unsigned vb = (unsigned)f2bf(adj_vals[e]);   // 15 significant bits
        pack[e] = c | (vb << 17);
    }
}

// ---- x -> xb[8][NN][32] bf16 transpose + drop_mask -> 1-bit pack ----
__global__ __launch_bounds__(256) void k_cvt_t(const float* __restrict__ x,
                                               const float* __restrict__ drop_mask,
                                               ushort* __restrict__ xb,
                                               unsigned* __restrict__ mbits) {
    __shared__ ushort ls[32][DD + 4];
    int t = threadIdx.x;
    size_t r0 = (size_t)blockIdx.x * 32;
    const float4* src = (const float4*)(x + r0 * DD);
#pragma unroll
    for (int u = 0; u < 8; ++u) {
        int idx = u * 256 + t;
        float4 v = src[idx];
        int row = idx >> 6, d4 = idx & 63;
        ushort* p = &ls[row][d4 * 4];
        p[0] = f2bf(v.x); p[1] = f2bf(v.y); p[2] = f2bf(v.z); p[3] = f2bf(v.w);
    }
    {   // mask pack: thread t -> row r = t>>3, 32-dim segment o = t&7
        int r = t >> 3, o = t & 7;
        const float4* mp = (const float4*)(drop_mask + (r0 + r) * DD + o * 32);
        unsigned bits = 0;
#pragma unroll
        for (int qq = 0; qq < 8; ++qq) {
            float4 m = mp[qq];
            bits |= (m.x != 0.f ? 1u : 0u) << (qq * 4 + 0);
            bits |= (m.y != 0.f ? 1u : 0u) << (qq * 4 + 1);
            bits |= (m.z != 0.f ? 1u : 0u) << (qq * 4 + 2);
            bits |= (m.w != 0.f ? 1u : 0u) << (qq * 4 + 3);
        }
        mbits[(r0 + r) * 8 + o] = bits;
    }
    __syncthreads();
    int c = t >> 5, r = t & 31;
    const uint4* s = (const uint4*)&ls[r][c * CH];
    uint4* dst = (uint4*)(xb + ((size_t)c * NN + r0 + r) * CH);
    dst[0] = s[0];
    dst[1] = s[1];
    dst[2] = s[2];
    dst[3] = s[3];
}

// ---- chunked SpMM1 + relu + bit-dropout -> hb: per-wave staging ----
// r14 structure; only change: packed u32 meta (1 load/edge, half replay).
// hb stores are the r14-proven two scalar u64 NT stores (the r15 ull2
// vector NT store destroyed L2 behavior: WRITE 58->455MB).
__global__ __launch_bounds__(256, 8) void k_chunk(
    const ushort* __restrict__ xb, const unsigned* __restrict__ pack,
    const int* __restrict__ row_ptr, const unsigned* __restrict__ mbits,
    ushort* __restrict__ hb)
{
    __shared__ unsigned meta[4][CAPW];
    int bid = blockIdx.x;
    int c = bid & 7;
    int q = bid >> 3;
    int wave = threadIdx.x >> 6, lane = threadIdx.x & 63;
    int g = lane >> 2, i = lane & 3;        // row-in-16, dim-octet
    const ushort* xc = xb + (size_t)c * NN * CH;
    unsigned* mw = meta[wave];

    for (int wg = q * 4 + wave; wg < WG16; wg += WPC) {
        int row0 = wg * 16;
        int row  = row0 + g;
        int e_start = __builtin_amdgcn_readfirstlane(row_ptr[row0]);
        int e_end   = __builtin_amdgcn_readfirstlane(row_ptr[row0 + 16]);
        int nstage  = min(e_end - e_start, CAPW);

        for (int t = lane; t < nstage; t += 64)
            mw[t] = pack[e_start + t];
        asm volatile("s_waitcnt lgkmcnt(0)" ::: "memory");
        __builtin_amdgcn_wave_barrier();

        int e0  = row_ptr[row];
        int cnt = row_ptr[row + 1] - e0;
        int eloc = e0 - e_start;
        float a0 = 0.f, a1 = 0.f, a2 = 0.f, a3 = 0.f;
        float a4 = 0.f, a5 = 0.f, a6 = 0.f, a7 = 0.f;

        if (eloc + cnt <= nstage) {          // staged path (always, in practice)
            int body = cnt & ~(UN2 - 1);
            int k = 0;
            for (; k < body; k += UN2) {
                unsigned mm[UN2];
#pragma unroll
                for (int u = 0; u < UN2; ++u) mm[u] = mw[eloc + k + u];
                uint4 xv[UN2];
#pragma unroll
                for (int u = 0; u < UN2; ++u)
                    xv[u] = *(const uint4*)(xc + (size_t)(mm[u] & COLMASK) * CH + i * 8);
#pragma unroll
                for (int u = 0; u < UN2; ++u) {
                    float v = punpack_v(mm[u]);
                    a0 = fmaf(v, bf2f(xv[u].x & 0xFFFFu), a0);
                    a1 = fmaf(v, bf2f(xv[u].x >> 16),     a1);
                    a2 = fmaf(v, bf2f(xv[u].y & 0xFFFFu), a2);
                    a3 = fmaf(v, bf2f(xv[u].y >> 16),     a3);
                    a4 = fmaf(v, bf2f(xv[u].z & 0xFFFFu), a4);
                    a5 = fmaf(v, bf2f(xv[u].z >> 16),     a5);
                    a6 = fmaf(v, bf2f(xv[u].w & 0xFFFFu), a6);
                    a7 = fmaf(v, bf2f(xv[u].w >> 16),     a7);
                }
            }
            if (k < cnt) {                   // one clamped tail batch
#pragma unroll
                for (int u = 0; u < UN2; ++u) {
                    int kk = k + u;
                    unsigned m = mw[eloc + min(kk, cnt - 1)];
                    float v = (kk < cnt) ? punpack_v(m) : 0.f;
                    uint4 xv = *(const uint4*)(xc + (size_t)(m & COLMASK) * CH + i * 8);
                    a0 = fmaf(v, bf2f(xv.x & 0xFFFFu), a0);
                    a1 = fmaf(v, bf2f(xv.x >> 16),     a1);
                    a2 = fmaf(v, bf2f(xv.y & 0xFFFFu), a2);
                    a3 = fmaf(v, bf2f(xv.y >> 16),     a3);
                    a4 = fmaf(v, bf2f(xv.z & 0xFFFFu), a4);
                    a5 = fmaf(v, bf2f(xv.z >> 16),     a5);
                    a6 = fmaf(v, bf2f(xv.w & 0xFFFFu), a6);
                    a7 = fmaf(v, bf2f(xv.w >> 16),     a7);
                }
            }
        } else {                             // overflow fallback (correctness net)
            for (int k = 0; k < cnt; ++k) {
                unsigned m = pack[e0 + k];
                float v = punpack_v(m);
                uint4 xv = *(const uint4*)(xc + (size_t)(m & COLMASK) * CH + i * 8);
                a0 = fmaf(v, bf2f(xv.x & 0xFFFFu), a0);
                a1 = fmaf(v, bf2f(xv.x >> 16),     a1);
                a2 = fmaf(v, bf2f(xv.y & 0xFFFFu), a2);
                a3 = fmaf(v, bf2f(xv.y >> 16),     a3);
                a4 = fmaf(v, bf2f(xv.z & 0xFFFFu), a4);
                a5 = fmaf(v, bf2f(xv.z >> 16),     a5);
                a6 = fmaf(v, bf2f(xv.w & 0xFFFFu), a6);
                a7 = fmaf(v, bf2f(xv.w >> 16),     a7);
            }
        }
        __builtin_amdgcn_wave_barrier();     // keep next staging after reads

        {
            unsigned mb = mbits[(size_t)row * 8 + c];
            unsigned mbyte = (mb >> (i * 8)) & 0xFFu;
            float h0 = (mbyte & 1u)   ? 2.f * fmaxf(a0, 0.f) : 0.f;
            float h1 = (mbyte & 2u)   ? 2.f * fmaxf(a1, 0.f) : 0.f;
            float h2 = (mbyte & 4u)   ? 2.f * fmaxf(a2, 0.f) : 0.f;
            float h3 = (mbyte & 8u)   ? 2.f * fmaxf(a3, 0.f) : 0.f;
            float h4 = (mbyte & 16u)  ? 2.f * fmaxf(a4, 0.f) : 0.f;
            float h5 = (mbyte & 32u)  ? 2.f * fmaxf(a5, 0.f) : 0.f;
            float h6 = (mbyte & 64u)  ? 2.f * fmaxf(a6, 0.f) : 0.f;
            float h7 = (mbyte & 128u) ? 2.f * fmaxf(a7, 0.f) : 0.f;
            size_t off = (size_t)row * DD + c * CH + i * 8;
            unsigned long long p0 =
                (unsigned long long)((unsigned)f2bf(h0) | ((unsigned)f2bf(h1) << 16)) |
                ((unsigned long long)((unsigned)f2bf(h2) | ((unsigned)f2bf(h3) << 16)) << 32);
            unsigned long long p1 =
                (unsigned long long)((unsigned)f2bf(h4) | ((unsigned)f2bf(h5) << 16)) |
                ((unsigned long long)((unsigned)f2bf(h6) | ((unsigned)f2bf(h7) << 16)) << 32);
            __builtin_nontemporal_store(p0, (unsigned long long*)(hb + off));
            __builtin_nontemporal_store(p1, (unsigned long long*)(hb + off + 4));
        }
    }
}

// ---- Linear(256->40) as register-tiled GEMM: 64 rows/block, W in LDS ----
__global__ __launch_bounds__(256) void k_linear(
    const ushort* __restrict__ hb, const float* __restrict__ W,
    const float* __restrict__ b, ushort* __restrict__ z)
{
    __shared__ float ws[CC][DD + 4];
    int t = threadIdx.x;
    for (int idx = t; idx < CC * (DD / 4); idx += 256) {
        int c = idx >> 6, k4 = idx & 63;
        float4 v = ((const float4*)(W + (size_t)c * DD))[k4];
        float* p = &ws[c][k4 * 4];
        p[0] = v.x; p[1] = v.y; p[2] = v.z; p[3] = v.w;
    }
    __syncthreads();

    int row = blockIdx.x * LROWS + (t >> 2);
    int cg = (t & 3) * 10;
    if (row >= NN) return;

    const uint4* hrow = (const uint4*)(hb + (size_t)row * DD);
    float acc[10] = {0.f, 0.f, 0.f, 0.f, 0.f, 0.f, 0.f, 0.f, 0.f, 0.f};

    for (int k8 = 0; k8 < DD / 8; ++k8) {
        uint4 hv = hrow[k8];
        float h0 = bf2f(hv.x & 0xFFFFu), h1 = bf2f(hv.x >> 16);
        float h2 = bf2f(hv.y & 0xFFFFu), h3 = bf2f(hv.y >> 16);
        float h4 = bf2f(hv.z & 0xFFFFu), h5 = bf2f(hv.z >> 16);
        float h6 = bf2f(hv.w & 0xFFFFu), h7 = bf2f(hv.w >> 16);
#pragma unroll
        for (int j = 0; j < 10; ++j) {
            const float* wp = &ws[cg + j][k8 * 8];
            float4 wa = *(const float4*)wp;
            float4 wb = *(const float4*)(wp + 4);
            acc[j] = fmaf(h0, wa.x, fmaf(h1, wa.y,
                     fmaf(h2, wa.z, fmaf(h3, wa.w, acc[j]))));
            acc[j] = fmaf(h4, wb.x, fmaf(h5, wb.y,
                     fmaf(h6, wb.z, fmaf(h7, wb.w, acc[j]))));
        }
    }
#pragma unroll
    for (int j = 0; j < 10; ++j)
        z[(size_t)row * CC + cg + j] = f2bf(acc[j] + b[cg + j]);
}

// ---- out = SpMM(z): 320-thread blocks, thread = (row, class); z bf16 ----
__global__ __launch_bounds__(320) void k_spmm2(
    const ushort* __restrict__ z, const float* __restrict__ adj_vals,
    const int* __restrict__ adj_col, const int* __restrict__ row_ptr,
    float* __restrict__ out)
{
    int t = threadIdx.x;
    int row = blockIdx.x * SROWS + t / CC;   // NN % 8 == 0, grid exact
    int cls = t % CC;

    int e0 = row_ptr[row], e1 = row_ptr[row + 1];
    float acc = 0.f;
    for (int base = e0; base < e1; base += UN2) {
        float vv[UN2]; int cc[UN2];
#pragma unroll
        for (int u = 0; u < UN2; ++u) {
            int idx = base + u;
            bool ok = idx < e1;
            idx = ok ? idx : e1 - 1;
            vv[u] = ok ? adj_vals[idx] : 0.f;
            cc[u] = adj_col[idx];
        }
        float za[UN2];
#pragma unroll
        for (int u = 0; u < UN2; ++u)
            za[u] = bf2f((unsigned)z[(size_t)cc[u] * CC + cls]);
#pragma unroll
        for (int u = 0; u < UN2; ++u)
            acc = fmaf(vv[u], za[u], acc);
    }
    out[(size_t)row * CC + cls] = acc;
}

extern "C" void kernel_launch(void* const* d_in, const int* in_sizes, int n_in,
                              void* d_out, int out_size, void* d_ws, size_t ws_size,
                              hipStream_t stream) {
    const float* x         = (const float*)d_in[0];
    const float* adj_vals  = (const float*)d_in[1];
    const float* W         = (const float*)d_in[2];
    const float* b         = (const float*)d_in[3];
    const float* drop_mask = (const float*)d_in[4];
    const int*   adj_row   = (const int*)d_in[5];
    const int*   adj_col   = (const int*)d_in[6];
    float* out = (float*)d_out;

    // ws: row_ptr | shared{pack u32[EE] -> later z bf16} | xb | hb | mbits
    char* wsp = (char*)d_ws;
    size_t rp_bytes = ((size_t)(NN + 1) * 4 + 255) & ~(size_t)255;
    size_t sh_bytes = (((size_t)EE * 4) + 255) & ~(size_t)255;
    size_t xb_bytes = (size_t)NN * DD * 2;
    size_t hb_bytes = (size_t)NN * DD * 2;
    int* row_ptr    = (int*)wsp;
    unsigned* pack  = (unsigned*)(wsp + rp_bytes);
    ushort* zbuf    = (ushort*)(wsp + rp_bytes);          // overlays pack
    ushort* xb      = (ushort*)(wsp + rp_bytes + sh_bytes);
    ushort* hb      = (ushort*)(wsp + rp_bytes + sh_bytes + xb_bytes);
    unsigned* mbits = (unsigned*)(wsp + rp_bytes + sh_bytes + xb_bytes + hb_bytes);

    hipLaunchKernelGGL(k_row_ptr, dim3((EE + 255) / 256), dim3(256), 0, stream,
                       adj_row, row_ptr);
    hipLaunchKernelGGL(k_pack, dim3(2048), dim3(256), 0, stream,
                       adj_vals, adj_col, pack);
    hipLaunchKernelGGL(k_cvt_t, dim3(NN / 32), dim3(256), 0, stream,
                       x, drop_mask, xb, mbits);
    hipLaunchKernelGGL(k_chunk, dim3(CHUNK_BLOCKS), dim3(256), 0, stream,
                       xb, pack, row_ptr, mbits, hb);
    hipLaunchKernelGGL(k_linear, dim3((NN + LROWS - 1) / LROWS), dim3(256), 0,
                       stream, hb, W, b, zbuf);
    hipLaunchKernelGGL(k_spmm2, dim3(NN / SROWS), dim3(320), 0, stream,
                       zbuf, adj_vals, adj_col, row_ptr, out);
}

// Round 17
// 441.862 us; speedup vs baseline: 1.4047x; 1.4026x over previous
//
#include <hip/hip_runtime.h>

#define NN 100000
#define EE 3200000
#define DD 256
#define CC 40
#define NCH 8
#define CH 32
#define UN2 8

#define CAPW 640              // staged edges per 16-row wave (avg 512, +5.7 sigma)
#define COHORT 256            // blocks per chunk
#define CHUNK_BLOCKS (COHORT * 8)
#define WPC (COHORT * 4)      // waves per chunk
#define WG16 (NN / 16)        // 6250 wave-groups of 16 rows
#define LROWS 64              // rows per k_linear block
#define SROWS 8               // rows per k_spmm2 block (320 threads)

__device__ __forceinline__ float bf2f(unsigned int u) {
    return __uint_as_float(u << 16);
}
__device__ __forceinline__ unsigned short f2bf(float f) {
    unsigned int t = __float_as_uint(f);
    return (unsigned short)((t + 0x7FFFu + ((t >> 16) & 1u)) >> 16);
}

// ---------------- CSR row_ptr from sorted adj_row ----------------
__global__ __launch_bounds__(256) void k_row_ptr(const int* __restrict__ adj_row,
                                                 int* __restrict__ row_ptr) {
    int e = blockIdx.x * 256 + threadIdx.x;
    if (e >= EE) return;
    int r = adj_row[e];
    int prev = (e == 0) ? -1 : adj_row[e - 1];
    for (int rr = prev + 1; rr <= r; ++rr) row_ptr[rr] = e;
    if (e == EE - 1) {
        for (int rr = r + 1; rr <= NN; ++rr) row_ptr[rr] = EE;
    }
}

// ---- x -> xb[8][NN][32] bf16 transpose + drop_mask -> 1-bit pack ----
__global__ __launch_bounds__(256) void k_cvt_t(const float* __restrict__ x,
                                               const float* __restrict__ drop_mask,
                                               ushort* __restrict__ xb,
                                               unsigned* __restrict__ mbits) {
    __shared__ ushort ls[32][DD + 4];
    int t = threadIdx.x;
    size_t r0 = (size_t)blockIdx.x * 32;
    const float4* src = (const float4*)(x + r0 * DD);
#pragma unroll
    for (int u = 0; u < 8; ++u) {
        int idx = u * 256 + t;
        float4 v = src[idx];
        int row = idx >> 6, d4 = idx & 63;
        ushort* p = &ls[row][d4 * 4];
        p[0] = f2bf(v.x); p[1] = f2bf(v.y); p[2] = f2bf(v.z); p[3] = f2bf(v.w);
    }
    {   // mask pack: thread t -> row r = t>>3, 32-dim segment o = t&7
        int r = t >> 3, o = t & 7;
        const float4* mp = (const float4*)(drop_mask + (r0 + r) * DD + o * 32);
        unsigned bits = 0;
#pragma unroll
        for (int qq = 0; qq < 8; ++qq) {
            float4 m = mp[qq];
            bits |= (m.x != 0.f ? 1u : 0u) << (qq * 4 + 0);
            bits |= (m.y != 0.f ? 1u : 0u) << (qq * 4 + 1);
            bits |= (m.z != 0.f ? 1u : 0u) << (qq * 4 + 2);
            bits |= (m.w != 0.f ? 1u : 0u) << (qq * 4 + 3);
        }
        mbits[(r0 + r) * 8 + o] = bits;
    }
    __syncthreads();
    int c = t >> 5, r = t & 31;
    const uint4* s = (const uint4*)&ls[r][c * CH];
    uint4* dst = (uint4*)(xb + ((size_t)c * NN + r0 + r) * CH);
    dst[0] = s[0];
    dst[1] = s[1];
    dst[2] = s[2];
    dst[3] = s[3];
}

// ---- chunked SpMM1 + relu + bit-dropout -> hb: per-wave staging (r11) ----
// Chunk c = bid&7 pinned to its XCD. Each wave owns 16 rows and stages its
// own contiguous edge range into a private LDS slice; no __syncthreads.
// 8 blocks/CU (160KB LDS), 32 waves/CU.
__global__ __launch_bounds__(256, 8) void k_chunk(
    const ushort* __restrict__ xb, const float* __restrict__ adj_vals,
    const int* __restrict__ adj_col, const int* __restrict__ row_ptr,
    const unsigned* __restrict__ mbits, ushort* __restrict__ hb)
{
    __shared__ uint2 meta[4][CAPW];
    int bid = blockIdx.x;
    int c = bid & 7;
    int q = bid >> 3;
    int wave = threadIdx.x >> 6, lane = threadIdx.x & 63;
    int g = lane >> 2, i = lane & 3;        // row-in-16, dim-octet
    const ushort* xc = xb + (size_t)c * NN * CH;
    uint2* mw = meta[wave];

    for (int wg = q * 4 + wave; wg < WG16; wg += WPC) {
        int row0 = wg * 16;
        int row  = row0 + g;
        int e_start = __builtin_amdgcn_readfirstlane(row_ptr[row0]);
        int e_end   = __builtin_amdgcn_readfirstlane(row_ptr[row0 + 16]);
        int nstage  = min(e_end - e_start, CAPW);

        for (int t = lane; t < nstage; t += 64) {
            uint2 m;
            m.x = (unsigned)adj_col[e_start + t];
            m.y = __float_as_uint(adj_vals[e_start + t]);
            mw[t] = m;
        }
        asm volatile("s_waitcnt lgkmcnt(0)" ::: "memory");
        __builtin_amdgcn_wave_barrier();

        int e0  = row_ptr[row];
        int cnt = row_ptr[row + 1] - e0;
        int eloc = e0 - e_start;
        float a0 = 0.f, a1 = 0.f, a2 = 0.f, a3 = 0.f;
        float a4 = 0.f, a5 = 0.f, a6 = 0.f, a7 = 0.f;

        if (eloc + cnt <= nstage) {          // staged path (always, in practice)
            int body = cnt & ~(UN2 - 1);
            int k = 0;
            for (; k < body; k += UN2) {
                uint2 mm[UN2];
#pragma unroll
                for (int u = 0; u < UN2; ++u) mm[u] = mw[eloc + k + u];
                uint4 xv[UN2];
#pragma unroll
                for (int u = 0; u < UN2; ++u)
                    xv[u] = *(const uint4*)(xc + (size_t)mm[u].x * CH + i * 8);
#pragma unroll
                for (int u = 0; u < UN2; ++u) {
                    float v = __uint_as_float(mm[u].y);
                    a0 = fmaf(v, bf2f(xv[u].x & 0xFFFFu), a0);
                    a1 = fmaf(v, bf2f(xv[u].x >> 16),     a1);
                    a2 = fmaf(v, bf2f(xv[u].y & 0xFFFFu), a2);
                    a3 = fmaf(v, bf2f(xv[u].y >> 16),     a3);
                    a4 = fmaf(v, bf2f(xv[u].z & 0xFFFFu), a4);
                    a5 = fmaf(v, bf2f(xv[u].z >> 16),     a5);
                    a6 = fmaf(v, bf2f(xv[u].w & 0xFFFFu), a6);
                    a7 = fmaf(v, bf2f(xv[u].w >> 16),     a7);
                }
            }
            if (k < cnt) {                   // one clamped tail batch
#pragma unroll
                for (int u = 0; u < UN2; ++u) {
                    int kk = k + u;
                    uint2 m = mw[eloc + min(kk, cnt - 1)];
                    float v = (kk < cnt) ? __uint_as_float(m.y) : 0.f;
                    uint4 xv = *(const uint4*)(xc + (size_t)m.x * CH + i * 8);
                    a0 = fmaf(v, bf2f(xv.x & 0xFFFFu), a0);
                    a1 = fmaf(v, bf2f(xv.x >> 16),     a1);
                    a2 = fmaf(v, bf2f(xv.y & 0xFFFFu), a2);
                    a3 = fmaf(v, bf2f(xv.y >> 16),     a3);
                    a4 = fmaf(v, bf2f(xv.z & 0xFFFFu), a4);
                    a5 = fmaf(v, bf2f(xv.z >> 16),     a5);
                    a6 = fmaf(v, bf2f(xv.w & 0xFFFFu), a6);
                    a7 = fmaf(v, bf2f(xv.w >> 16),     a7);
                }
            }
        } else {                             // overflow fallback (correctness net)
            for (int k = 0; k < cnt; ++k) {
                int idx = e0 + k;
                float v = adj_vals[idx];
                int col = adj_col[idx];
                uint4 xv = *(const uint4*)(xc + (size_t)col * CH + i * 8);
                a0 = fmaf(v, bf2f(xv.x & 0xFFFFu), a0);
                a1 = fmaf(v, bf2f(xv.x >> 16),     a1);
                a2 = fmaf(v, bf2f(xv.y & 0xFFFFu), a2);
                a3 = fmaf(v, bf2f(xv.y >> 16),     a3);
                a4 = fmaf(v, bf2f(xv.z & 0xFFFFu), a4);
                a5 = fmaf(v, bf2f(xv.z >> 16),     a5);
                a6 = fmaf(v, bf2f(xv.w & 0xFFFFu), a6);
                a7 = fmaf(v, bf2f(xv.w >> 16),     a7);
            }
        }
        __builtin_amdgcn_wave_barrier();     // keep next staging after reads

        {
            unsigned mb = mbits[(size_t)row * 8 + c];
            unsigned mbyte = (mb >> (i * 8)) & 0xFFu;
            float h0 = (mbyte & 1u)   ? 2.f * fmaxf(a0, 0.f) : 0.f;
            float h1 = (mbyte & 2u)   ? 2.f * fmaxf(a1, 0.f) : 0.f;
            float h2 = (mbyte & 4u)   ? 2.f * fmaxf(a2, 0.f) : 0.f;
            float h3 = (mbyte & 8u)   ? 2.f * fmaxf(a3, 0.f) : 0.f;
            float h4 = (mbyte & 16u)  ? 2.f * fmaxf(a4, 0.f) : 0.f;
            float h5 = (mbyte & 32u)  ? 2.f * fmaxf(a5, 0.f) : 0.f;
            float h6 = (mbyte & 64u)  ? 2.f * fmaxf(a6, 0.f) : 0.f;
            float h7 = (mbyte & 128u) ? 2.f * fmaxf(a7, 0.f) : 0.f;
            size_t off = (size_t)row * DD + c * CH + i * 8;
            unsigned long long p0 =
                (unsigned long long)((unsigned)f2bf(h0) | ((unsigned)f2bf(h1) << 16)) |
                ((unsigned long long)((unsigned)f2bf(h2) | ((unsigned)f2bf(h3) << 16)) << 32);
            unsigned long long p1 =
                (unsigned long long)((unsigned)f2bf(h4) | ((unsigned)f2bf(h5) << 16)) |
                ((unsigned long long)((unsigned)f2bf(h6) | ((unsigned)f2bf(h7) << 16)) << 32);
            __builtin_nontemporal_store(p0, (unsigned long long*)(hb + off));
            __builtin_nontemporal_store(p1, (unsigned long long*)(hb + off + 4));
        }
    }
}

// ---- Linear(256->40) as register-tiled GEMM: 64 rows/block, W in LDS ----
__global__ __launch_bounds__(256) void k_linear(
    const ushort* __restrict__ hb, const float* __restrict__ W,
    const float* __restrict__ b, ushort* __restrict__ z)
{
    __shared__ float ws[CC][DD + 4];
    int t = threadIdx.x;
    for (int idx = t; idx < CC * (DD / 4); idx += 256) {
        int c = idx >> 6, k4 = idx & 63;
        float4 v = ((const float4*)(W + (size_t)c * DD))[k4];
        float* p = &ws[c][k4 * 4];
        p[0] = v.x; p[1] = v.y; p[2] = v.z; p[3] = v.w;
    }
    __syncthreads();

    int row = blockIdx.x * LROWS + (t >> 2);
    int cg = (t & 3) * 10;
    if (row >= NN) return;

    const uint4* hrow = (const uint4*)(hb + (size_t)row * DD);
    float acc[10] = {0.f, 0.f, 0.f, 0.f, 0.f, 0.f, 0.f, 0.f, 0.f, 0.f};

    for (int k8 = 0; k8 < DD / 8; ++k8) {
        uint4 hv = hrow[k8];
        float h0 = bf2f(hv.x & 0xFFFFu), h1 = bf2f(hv.x >> 16);
        float h2 = bf2f(hv.y & 0xFFFFu), h3 = bf2f(hv.y >> 16);
        float h4 = bf2f(hv.z & 0xFFFFu), h5 = bf2f(hv.z >> 16);
        float h6 = bf2f(hv.w & 0xFFFFu), h7 = bf2f(hv.w >> 16);
#pragma unroll
        for (int j = 0; j < 10; ++j) {
            const float* wp = &ws[cg + j][k8 * 8];
            float4 wa = *(const float4*)wp;
            float4 wb = *(const float4*)(wp + 4);
            acc[j] = fmaf(h0, wa.x, fmaf(h1, wa.y,
                     fmaf(h2, wa.z, fmaf(h3, wa.w, acc[j]))));
            acc[j] = fmaf(h4, wb.x, fmaf(h5, wb.y,
                     fmaf(h6, wb.z, fmaf(h7, wb.w, acc[j]))));
        }
    }
#pragma unroll
    for (int j = 0; j < 10; ++j)
        z[(size_t)row * CC + cg + j] = f2bf(acc[j] + b[cg + j]);
}

// ---- out = SpMM(z): 320-thread blocks, thread = (row, class); z bf16 ----
__global__ __launch_bounds__(320) void k_spmm2(
    const ushort* __restrict__ z, const float* __restrict__ adj_vals,
    const int* __restrict__ adj_col, const int* __restrict__ row_ptr,
    float* __restrict__ out)
{
    int t = threadIdx.x;
    int row = blockIdx.x * SROWS + t / CC;   // NN % 8 == 0, grid exact
    int cls = t % CC;

    int e0 = row_ptr[row], e1 = row_ptr[row + 1];
    float acc = 0.f;
    for (int base = e0; base < e1; base += UN2) {
        float vv[UN2]; int cc[UN2];
#pragma unroll
        for (int u = 0; u < UN2; ++u) {
            int idx = base + u;
            bool ok = idx < e1;
            idx = ok ? idx : e1 - 1;
            vv[u] = ok ? adj_vals[idx] : 0.f;
            cc[u] = adj_col[idx];
        }
        float za[UN2];
#pragma unroll
        for (int u = 0; u < UN2; ++u)
            za[u] = bf2f((unsigned)z[(size_t)cc[u] * CC + cls]);
#pragma unroll
        for (int u = 0; u < UN2; ++u)
            acc = fmaf(vv[u], za[u], acc);
    }
    out[(size_t)row * CC + cls] = acc;
}

extern "C" void kernel_launch(void* const* d_in, const int* in_sizes, int n_in,
                              void* d_out, int out_size, void* d_ws, size_t ws_size,
                              hipStream_t stream) {
    const float* x         = (const float*)d_in[0];
    const float* adj_vals  = (const float*)d_in[1];
    const float* W         = (const float*)d_in[2];
    const float* b         = (const float*)d_in[3];
    const float* drop_mask = (const float*)d_in[4];
    const int*   adj_row   = (const int*)d_in[5];
    const int*   adj_col   = (const int*)d_in[6];
    float* out = (float*)d_out;

    // ws: row_ptr | z(bf16) | xb[8][NN][32] | hb[NN][256] | mbits[NN][8]u32  (~114MB)
    char* wsp = (char*)d_ws;
    size_t rp_bytes = ((size_t)(NN + 1) * 4 + 255) & ~(size_t)255;
    size_t z_bytes  = (((size_t)NN * CC * 2) + 255) & ~(size_t)255;
    size_t xb_bytes = (size_t)NN * DD * 2;
    size_t hb_bytes = (size_t)NN * DD * 2;
    int* row_ptr    = (int*)wsp;
    ushort* zbuf    = (ushort*)(wsp + rp_bytes);
    ushort* xb      = (ushort*)(wsp + rp_bytes + z_bytes);
    ushort* hb      = (ushort*)(wsp + rp_bytes + z_bytes + xb_bytes);
    unsigned* mbits = (unsigned*)(wsp + rp_bytes + z_bytes + xb_bytes + hb_bytes);

    hipLaunchKernelGGL(k_row_ptr, dim3((EE + 255) / 256), dim3(256), 0, stream,
                       adj_row, row_ptr);
    hipLaunchKernelGGL(k_cvt_t, dim3(NN / 32), dim3(256), 0, stream,
                       x, drop_mask, xb, mbits);
    hipLaunchKernelGGL(k_chunk, dim3(CHUNK_BLOCKS), dim3(256), 0, stream,
                       xb, adj_vals, adj_col, row_ptr, mbits, hb);
    hipLaunchKernelGGL(k_linear, dim3((NN + LROWS - 1) / LROWS), dim3(256), 0,
                       stream, hb, W, b, zbuf);
    hipLaunchKernelGGL(k_spmm2, dim3(NN / SROWS), dim3(320), 0, stream,
                       zbuf, adj_vals, adj_col, row_ptr, out);
}